// Round 5
// baseline (264.825 us; speedup 1.0000x reference)
//
#include <hip/hip_runtime.h>

typedef unsigned short u16;
typedef __bf16 bf16x8 __attribute__((ext_vector_type(8)));
typedef float floatx4 __attribute__((ext_vector_type(4)));

// fp32 -> bf16 via HW cvt (RNE, single VALU op; compiler packs pairs into
// v_cvt_pk_bf16_f32). Replaces the 4-op bit-hack — bit-identical on normals.
__device__ inline u16 f2bf(float x) {
    __bf16 b = (__bf16)x;
    return __builtin_bit_cast(u16, b);
}

__device__ inline floatx4 fzero() {
    floatx4 z = {0.f, 0.f, 0.f, 0.f};
    return z;
}

#if defined(__has_builtin)
#if __has_builtin(__builtin_amdgcn_exp2f)
#define EXP2F(x) __builtin_amdgcn_exp2f(x)
#endif
#endif
#ifndef EXP2F
#define EXP2F(x) exp2f(x)
#endif

// Load 8 contiguous elements as a bf16x8 fragment; fp32 source converts RNE.
template <bool F32>
__device__ inline bf16x8 ld8(const void* base, size_t off) {
    if constexpr (F32) {
        const float* p = (const float*)base + off;
        float4 a = *(const float4*)p;
        float4 b = *(const float4*)(p + 4);
        union { u16 u[8]; bf16x8 v; } t;
        t.u[0] = f2bf(a.x); t.u[1] = f2bf(a.y); t.u[2] = f2bf(a.z); t.u[3] = f2bf(a.w);
        t.u[4] = f2bf(b.x); t.u[5] = f2bf(b.y); t.u[6] = f2bf(b.z); t.u[7] = f2bf(b.w);
        return t.v;
    } else {
        return *(const bf16x8*)((const u16*)base + off);
    }
}

// Async global->LDS, 16B per lane. LDS dest MUST be wave-uniform; HW appends
// lane*16 itself (m104/m108). Callers pass the wave-uniform base only.
typedef __attribute__((address_space(1))) const unsigned int as1_u32;
typedef __attribute__((address_space(3))) unsigned int as3_u32;
__device__ inline void gld_lds16(const void* g, void* l) {
    __builtin_amdgcn_global_load_lds((as1_u32*)g, (as3_u32*)l, 16, 0, 0);
}

// XOR-swizzled LDS accessor for 64-el (128 B) rows.
// byte ^= (row&7)<<4 : bijective within each 8-row stripe, spreads the
// 16B slots of a column across all 8 slots -> conflict-free ds_read_b128.
__device__ inline u16* swz_ptr(u16* buf, int row, int col) {
    return (u16*)((char*)buf + row * 128 + ((col * 2) ^ ((row & 7) << 4)));
}

// ---------------------------------------------------------------------------
// fp32 -> bf16 bulk convert, ALL THREE tensors in one dispatch (dst regions
// are contiguous in the workspace: [XB | WAB | WPB]).
// ---------------------------------------------------------------------------
__global__ __launch_bounds__(256) void cvt_all(const float* __restrict__ x,
                                               const float* __restrict__ wa,
                                               const float* __restrict__ wp,
                                               u16* __restrict__ dst) {
    const int XB8 = 1048576, WAB8 = 393216;    // 8-el groups per tensor
    int i = blockIdx.x * 256 + threadIdx.x;    // grid covers exactly total
    const float* src; size_t off;
    if (i < XB8)             { src = x;  off = (size_t)i * 8; }
    else if (i < XB8 + WAB8) { src = wa; off = (size_t)(i - XB8) * 8; }
    else                     { src = wp; off = (size_t)(i - XB8 - WAB8) * 8; }
    *(bf16x8*)(dst + (size_t)i * 8) = ld8<true>(src, off);
}

// ---------------------------------------------------------------------------
// C[M,N] = A[M,K] * B[N,K]^T.
// bf16 path: minimum-2-phase double-buffer (T3): issue next tile's
// global_load_lds BEFORE current tile's ds_read+MFMA, ONE barrier per K-step.
// ---------------------------------------------------------------------------
#define BK 32

template <bool AF32, bool BF32, bool CF32>
__global__ __launch_bounds__(256) void gemm_bt(const void* __restrict__ Ap,
                                               const void* __restrict__ Bp,
                                               void* __restrict__ Cp,
                                               int M, int N, int K) {
    __shared__ alignas(16) u16 As[2][128 * BK];
    __shared__ alignas(16) u16 Bs[2][128 * BK];

    const int tid  = threadIdx.x;
    const int lane = tid & 63;
    const int wave = tid >> 6;
    const int wm = (wave >> 1) * 64;
    const int wn = (wave & 1) * 64;
    const int tm = blockIdx.y * 128;
    const int tn = blockIdx.x * 128;
    const int l15 = lane & 15;
    const int l4  = lane >> 4;

    const int srow = tid >> 2;
    const int scol = (tid & 3) * 8;

    floatx4 acc[4][4];
#pragma unroll
    for (int i = 0; i < 4; i++)
#pragma unroll
        for (int j = 0; j < 4; j++) acc[i][j] = fzero();

    if constexpr (!AF32 && !BF32) {
        // Per-lane GLOBAL source is allowed; LDS dest is the wave-uniform base,
        // HW writes lane l at base + l*16 -> LDS element tid*8 overall.
        const u16* Ag = (const u16*)Ap + (size_t)(tm + srow) * K + scol;
        const u16* Bg = (const u16*)Bp + (size_t)(tn + srow) * K + scol;

        auto stage = [&](int buf, int k0) {
            gld_lds16(Ag + k0,                  &As[buf][wave * 512]);
            gld_lds16(Ag + k0 + (size_t)64 * K, &As[buf][2048 + wave * 512]);
            gld_lds16(Bg + k0,                  &Bs[buf][wave * 512]);
            gld_lds16(Bg + k0 + (size_t)64 * K, &Bs[buf][2048 + wave * 512]);
        };

        stage(0, 0);
        __syncthreads();                       // prologue tile landed
        int cur = 0;
        const int nk = K / BK;
        for (int t = 0; t < nk; t++) {
            if (t + 1 < nk) stage(cur ^ 1, (t + 1) * BK);  // issue early

            bf16x8 af[4], bfv[4];
#pragma unroll
            for (int i = 0; i < 4; i++)
                af[i] = *(const bf16x8*)&As[cur][(wm + i * 16 + l15) * BK + l4 * 8];
#pragma unroll
            for (int j = 0; j < 4; j++)
                bfv[j] = *(const bf16x8*)&Bs[cur][(wn + j * 16 + l15) * BK + l4 * 8];
#pragma unroll
            for (int i = 0; i < 4; i++)
#pragma unroll
                for (int j = 0; j < 4; j++)
                    acc[i][j] = __builtin_amdgcn_mfma_f32_16x16x32_bf16(af[i], bfv[j], acc[i][j], 0, 0, 0);

            __syncthreads();                   // reads done + next tile landed
            cur ^= 1;
        }
    } else {
        for (int k0 = 0; k0 < K; k0 += BK) {
            bf16x8 av[2], bv[2];
#pragma unroll
            for (int q = 0; q < 2; q++) {
                av[q] = ld8<AF32>(Ap, (size_t)(tm + srow + q * 64) * K + k0 + scol);
                bv[q] = ld8<BF32>(Bp, (size_t)(tn + srow + q * 64) * K + k0 + scol);
            }
            __syncthreads();
#pragma unroll
            for (int q = 0; q < 2; q++) {
                *(bf16x8*)&As[0][(srow + q * 64) * BK + scol] = av[q];
                *(bf16x8*)&Bs[0][(srow + q * 64) * BK + scol] = bv[q];
            }
            __syncthreads();

            bf16x8 af[4], bfv[4];
#pragma unroll
            for (int i = 0; i < 4; i++)
                af[i] = *(const bf16x8*)&As[0][(wm + i * 16 + l15) * BK + l4 * 8];
#pragma unroll
            for (int j = 0; j < 4; j++)
                bfv[j] = *(const bf16x8*)&Bs[0][(wn + j * 16 + l15) * BK + l4 * 8];
#pragma unroll
            for (int i = 0; i < 4; i++)
#pragma unroll
                for (int j = 0; j < 4; j++)
                    acc[i][j] = __builtin_amdgcn_mfma_f32_16x16x32_bf16(af[i], bfv[j], acc[i][j], 0, 0, 0);
        }
    }

#pragma unroll
    for (int i = 0; i < 4; i++)
#pragma unroll
        for (int j = 0; j < 4; j++)
#pragma unroll
            for (int r = 0; r < 4; r++) {
                int row = tm + wm + i * 16 + l4 * 4 + r;
                int col = tn + wn + j * 16 + l15;
                if constexpr (CF32)
                    ((float*)Cp)[(size_t)row * N + col] = acc[i][j][r];
                else
                    ((u16*)Cp)[(size_t)row * N + col] = f2bf(acc[i][j][r]);
            }
}

// ---------------------------------------------------------------------------
// V transpose: qkv v-part [b][t][h][dh] -> vT [bh][dh][t]
// ---------------------------------------------------------------------------
__global__ __launch_bounds__(256) void transpose_v(const u16* __restrict__ qkv,
                                                   u16* __restrict__ vT) {
    __shared__ alignas(16) u16 Ts[64 * 80];
    const int bh = blockIdx.x;
    const int b = bh >> 4, h = bh & 15;
    const int t0 = blockIdx.y * 64;
    const int tid = threadIdx.x;
    const int r = tid >> 3;
    const int c = tid & 7;
#pragma unroll
    for (int p = 0; p < 2; p++) {
        int tr = r + p * 32;
        *(bf16x8*)&Ts[tr * 80 + c * 8] =
            *(const bf16x8*)&qkv[(size_t)(b * 2048 + t0 + tr) * 3072 + 2048 + h * 64 + c * 8];
    }
    __syncthreads();
#pragma unroll
    for (int p = 0; p < 2; p++) {
        int dr = r + p * 32;
        union { u16 u[8]; bf16x8 v; } t;
#pragma unroll
        for (int i = 0; i < 8; i++) t.u[i] = Ts[(c * 8 + i) * 80 + dr];
        *(bf16x8*)&vT[(size_t)bh * 131072 + (size_t)dr * 2048 + t0 + c * 8] = t.v;
    }
}

// ---------------------------------------------------------------------------
// Flash attention, causal, no online rescaling (scores bounded). Verified
// round-1/4 structure (0 bank conflicts). This round: VALU diet —
//  (a) HW bf16 casts (v_cvt_pk) for the P-store,
//  (b) softmax denominator via MFMA against an all-ones B-fragment
//      (2 MFMA/tile replace 16 VALU adds + the 16-step shuffle epilogue).
// ---------------------------------------------------------------------------
template <bool USE_VT>
__global__ __launch_bounds__(256) void attn2(const u16* __restrict__ qkv,
                                             const u16* __restrict__ vT,
                                             u16* __restrict__ y) {
    const int T = 2048, CW = 3072;
    __shared__ alignas(16) u16 KP[64 * 64];   // K tile [key][dh]
    __shared__ alignas(16) u16 Vt[64 * 64];   // V^T tile [dh][key]
    __shared__ alignas(16) u16 PB[64 * 64];   // P tile [qrow][key], wave-private rows

    const int tid  = threadIdx.x;
    const int lane = tid & 63;
    const int wave = tid >> 6;
    const int l15 = lane & 15;
    const int l4  = lane >> 4;

    const int bh = blockIdx.x;
    const int qt = 31 - blockIdx.y;            // heavy tiles dispatched first
    const int b = bh >> 4, h = bh & 15;
    const int q0 = qt * 64;

    const size_t base = (size_t)b * T * CW + h * 64;
    const u16* qp = qkv + base;
    const u16* kp = qkv + base + 1024;
    const u16* vp = qkv + base + 2048;
    const u16* vtp = USE_VT ? (vT + (size_t)bh * 131072) : nullptr;

    bf16x8 qf[2];
    {
        int qrow = q0 + wave * 16 + l15;
        qf[0] = *(const bf16x8*)&qp[(size_t)qrow * CW + l4 * 8];
        qf[1] = *(const bf16x8*)&qp[(size_t)qrow * CW + 32 + l4 * 8];
    }

    // all-ones B-fragment for the denominator MFMA
    bf16x8 ones;
#pragma unroll
    for (int i = 0; i < 8; i++) ones[i] = (__bf16)1.0f;

    const float C2 = 0.18033688f;              // (1/8) * log2(e)
    floatx4 Lacc = fzero();                    // rowsum accumulator (all cols equal)
    floatx4 Oacc[4];
#pragma unroll
    for (int cf = 0; cf < 4; cf++) Oacc[cf] = fzero();

    const int sr = tid >> 3;                   // 0..31 (staging row)
    const int sc = tid & 7;                    // 0..7  (staging 16B chunk)

    bf16x8 kreg[2], vreg[2];
    auto stage_load = [&](int kt) {
        const int t0 = kt * 64;
#pragma unroll
        for (int p = 0; p < 2; p++)
            kreg[p] = *(const bf16x8*)&kp[(size_t)(t0 + sr + p * 32) * CW + sc * 8];
        if constexpr (USE_VT) {
#pragma unroll
            for (int p = 0; p < 2; p++)
                vreg[p] = *(const bf16x8*)&vtp[(size_t)(sr + p * 32) * 2048 + t0 + sc * 8];
        } else {
            const int dh = tid & 63;
            const int tb = wave * 8;
#pragma unroll
            for (int p = 0; p < 2; p++) {
                union { u16 u[8]; bf16x8 v; } tmp;
#pragma unroll
                for (int i = 0; i < 8; i++)
                    tmp.u[i] = vp[(size_t)(t0 + tb + p * 32 + i) * CW + dh];
                vreg[p] = tmp.v;
            }
        }
    };

    stage_load(0);

    for (int kt = 0; kt <= qt; kt++) {
        const int t0 = kt * 64;
        __syncthreads();                       // all waves' KP/Vt reads of prev tile done

        // commit staged K/V (compiler waits vmcnt before these ds_writes)
#pragma unroll
        for (int p = 0; p < 2; p++)
            *(bf16x8*)swz_ptr(KP, sr + p * 32, sc * 8) = kreg[p];
        if constexpr (USE_VT) {
#pragma unroll
            for (int p = 0; p < 2; p++)
                *(bf16x8*)swz_ptr(Vt, sr + p * 32, sc * 8) = vreg[p];
        } else {
            const int dh = tid & 63;
            const int tb = wave * 8;
#pragma unroll
            for (int p = 0; p < 2; p++)
                *(bf16x8*)swz_ptr(Vt, dh, tb + p * 32) = vreg[p];
        }
        __syncthreads();

        if (kt < qt) stage_load(kt + 1);       // prefetch next tile under compute

        // S = Q*K^T, per 16-key block: mask, exp2, P-store (short live ranges)
#pragma unroll
        for (int j = 0; j < 4; j++) {
            bf16x8 k0f = *(const bf16x8*)swz_ptr(KP, j * 16 + l15, l4 * 8);
            bf16x8 k1f = *(const bf16x8*)swz_ptr(KP, j * 16 + l15, 32 + l4 * 8);
            floatx4 s = fzero();
            s = __builtin_amdgcn_mfma_f32_16x16x32_bf16(qf[0], k0f, s, 0, 0, 0);
            s = __builtin_amdgcn_mfma_f32_16x16x32_bf16(qf[1], k1f, s, 0, 0, 0);
            float pj[4];
            if (kt == qt) {
#pragma unroll
                for (int r = 0; r < 4; r++) {
                    int qrow = q0 + wave * 16 + l4 * 4 + r;
                    int krow = t0 + j * 16 + l15;
                    float e = (krow <= qrow) ? s[r] * C2 : -1.0e30f;
                    pj[r] = EXP2F(e);
                }
            } else {
#pragma unroll
                for (int r = 0; r < 4; r++) pj[r] = EXP2F(s[r] * C2);
            }
            // wave-private rows; same-wave DS ordering -> no barrier needed
#pragma unroll
            for (int r = 0; r < 4; r++)
                *swz_ptr(PB, wave * 16 + l4 * 4 + r, j * 16 + l15) = f2bf(pj[r]);
        }

        // P A-frags (this wave's own 16 rows) + PV + denominator MFMA
        bf16x8 pf0 = *(const bf16x8*)swz_ptr(PB, wave * 16 + l15, l4 * 8);
        bf16x8 pf1 = *(const bf16x8*)swz_ptr(PB, wave * 16 + l15, 32 + l4 * 8);
        Lacc = __builtin_amdgcn_mfma_f32_16x16x32_bf16(pf0, ones, Lacc, 0, 0, 0);
        Lacc = __builtin_amdgcn_mfma_f32_16x16x32_bf16(pf1, ones, Lacc, 0, 0, 0);
#pragma unroll
        for (int cf = 0; cf < 4; cf++) {
            bf16x8 v0f = *(const bf16x8*)swz_ptr(Vt, cf * 16 + l15, l4 * 8);
            bf16x8 v1f = *(const bf16x8*)swz_ptr(Vt, cf * 16 + l15, 32 + l4 * 8);
            Oacc[cf] = __builtin_amdgcn_mfma_f32_16x16x32_bf16(pf0, v0f, Oacc[cf], 0, 0, 0);
            Oacc[cf] = __builtin_amdgcn_mfma_f32_16x16x32_bf16(pf1, v1f, Oacc[cf], 0, 0, 0);
        }
    }

    // epilogue: Lacc[r] already holds the full row sum in every lane column
#pragma unroll
    for (int r = 0; r < 4; r++) {
        float inv = 1.0f / Lacc[r];
        int qrow = q0 + wave * 16 + l4 * 4 + r;
        size_t orow = ((size_t)b * T + qrow) * 1024 + h * 64;
#pragma unroll
        for (int cf = 0; cf < 4; cf++)
            y[orow + cf * 16 + l15] = f2bf(Oacc[cf][r] * inv);
    }
}

extern "C" void kernel_launch(void* const* d_in, const int* in_sizes, int n_in,
                              void* d_out, int out_size, void* d_ws, size_t ws_size,
                              hipStream_t stream) {
    const float* x      = (const float*)d_in[0];   // [8192,1024] fp32
    const float* w_attn = (const float*)d_in[1];   // [3072,1024] fp32
    const float* w_proj = (const float*)d_in[2];   // [1024,1024] fp32
    float* out = (float*)d_out;                    // [8192,1024] fp32

    const size_t QKV = (size_t)8192 * 3072;
    const size_t Y   = (size_t)8192 * 1024;
    const size_t VTE = (size_t)64 * 64 * 2048;     // 8.4M
    const size_t XB  = (size_t)8192 * 1024;
    const size_t WAB = (size_t)3072 * 1024;
    const size_t WPB = (size_t)1024 * 1024;

    u16* qkv = (u16*)d_ws;
    u16* yb  = qkv + QKV;

    const bool full = ws_size >= (QKV + Y + VTE + XB + WAB + WPB) * sizeof(u16); // 104 MiB
    const bool mid  = ws_size >= (QKV + Y + VTE) * sizeof(u16);                  // 80 MiB
    if (ws_size < (QKV + Y) * sizeof(u16)) return;                               // 64 MiB floor

    dim3 blk(256);
    dim3 g1(3072 / 128, 8192 / 128), g2(1024 / 128, 8192 / 128);
    dim3 ga(64, 32);

    if (full) {
        u16* vT  = yb + Y;
        u16* xb  = vT + VTE;                       // xb|wab|wpb contiguous
        cvt_all<<<6144, blk, 0, stream>>>(x, w_attn, w_proj, xb);
        u16* wab = xb + XB;
        u16* wpb = wab + WAB;
        gemm_bt<false, false, false><<<g1, blk, 0, stream>>>(xb, wab, qkv, 8192, 3072, 1024);
        transpose_v<<<ga, blk, 0, stream>>>(qkv, vT);
        attn2<true><<<ga, blk, 0, stream>>>(qkv, vT, yb);
        gemm_bt<false, false, true><<<g2, blk, 0, stream>>>(yb, wpb, out, 8192, 1024, 1024);
    } else if (mid) {
        u16* vT = yb + Y;
        gemm_bt<true, true, false><<<g1, blk, 0, stream>>>(x, w_attn, qkv, 8192, 3072, 1024);
        transpose_v<<<ga, blk, 0, stream>>>(qkv, vT);
        attn2<true><<<ga, blk, 0, stream>>>(qkv, vT, yb);
        gemm_bt<false, true, true><<<g2, blk, 0, stream>>>(yb, w_proj, out, 8192, 1024, 1024);
    } else {
        gemm_bt<true, true, false><<<g1, blk, 0, stream>>>(x, w_attn, qkv, 8192, 3072, 1024);
        attn2<false><<<ga, blk, 0, stream>>>(qkv, nullptr, yb);
        gemm_bt<false, true, true><<<g2, blk, 0, stream>>>(yb, w_proj, out, 8192, 1024, 1024);
    }
}

// Round 6
// 251.252 us; speedup vs baseline: 1.0540x; 1.0540x over previous
//
#include <hip/hip_runtime.h>

typedef unsigned short u16;
typedef __bf16 bf16x8 __attribute__((ext_vector_type(8)));
typedef float floatx4 __attribute__((ext_vector_type(4)));

// fp32 -> bf16 via HW cvt (RNE, single VALU op; compiler packs pairs into
// v_cvt_pk_bf16_f32).
__device__ inline u16 f2bf(float x) {
    __bf16 b = (__bf16)x;
    return __builtin_bit_cast(u16, b);
}

__device__ inline floatx4 fzero() {
    floatx4 z = {0.f, 0.f, 0.f, 0.f};
    return z;
}

#if defined(__has_builtin)
#if __has_builtin(__builtin_amdgcn_exp2f)
#define EXP2F(x) __builtin_amdgcn_exp2f(x)
#endif
#endif
#ifndef EXP2F
#define EXP2F(x) exp2f(x)
#endif

// Load 8 contiguous elements as a bf16x8 fragment; fp32 source converts RNE.
template <bool F32>
__device__ inline bf16x8 ld8(const void* base, size_t off) {
    if constexpr (F32) {
        const float* p = (const float*)base + off;
        float4 a = *(const float4*)p;
        float4 b = *(const float4*)(p + 4);
        union { u16 u[8]; bf16x8 v; } t;
        t.u[0] = f2bf(a.x); t.u[1] = f2bf(a.y); t.u[2] = f2bf(a.z); t.u[3] = f2bf(a.w);
        t.u[4] = f2bf(b.x); t.u[5] = f2bf(b.y); t.u[6] = f2bf(b.z); t.u[7] = f2bf(b.w);
        return t.v;
    } else {
        return *(const bf16x8*)((const u16*)base + off);
    }
}

// Async global->LDS, 16B per lane. LDS dest MUST be wave-uniform; HW appends
// lane*16 itself (m104/m108). Callers pass the wave-uniform base only.
typedef __attribute__((address_space(1))) const unsigned int as1_u32;
typedef __attribute__((address_space(3))) unsigned int as3_u32;
__device__ inline void gld_lds16(const void* g, void* l) {
    __builtin_amdgcn_global_load_lds((as1_u32*)g, (as3_u32*)l, 16, 0, 0);
}

// XOR-swizzled LDS accessor for 64-el (128 B) rows.
// byte ^= (row&7)<<4 : bijective within each 8-row stripe, spreads the
// 16B slots of a column across all 8 slots -> conflict-free ds_read_b128.
__device__ inline u16* swz_ptr(u16* buf, int row, int col) {
    return (u16*)((char*)buf + row * 128 + ((col * 2) ^ ((row & 7) << 4)));
}

// ---------------------------------------------------------------------------
// fp32 -> bf16 bulk convert, ALL THREE tensors in one dispatch (dst regions
// are contiguous in the workspace: [XB | WAB | WPB]).
// ---------------------------------------------------------------------------
__global__ __launch_bounds__(256) void cvt_all(const float* __restrict__ x,
                                               const float* __restrict__ wa,
                                               const float* __restrict__ wp,
                                               u16* __restrict__ dst) {
    const int XB8 = 1048576, WAB8 = 393216;    // 8-el groups per tensor
    int i = blockIdx.x * 256 + threadIdx.x;    // grid covers exactly total
    const float* src; size_t off;
    if (i < XB8)             { src = x;  off = (size_t)i * 8; }
    else if (i < XB8 + WAB8) { src = wa; off = (size_t)(i - XB8) * 8; }
    else                     { src = wp; off = (size_t)(i - XB8 - WAB8) * 8; }
    *(bf16x8*)(dst + (size_t)i * 8) = ld8<true>(src, off);
}

// ---------------------------------------------------------------------------
// C[M,N] = A[M,K] * B[N,K]^T.
// bf16 path: minimum-2-phase double-buffer (T3): issue next tile's
// global_load_lds BEFORE current tile's ds_read+MFMA, ONE barrier per K-step.
// ---------------------------------------------------------------------------
#define BK 32

template <bool AF32, bool BF32, bool CF32>
__global__ __launch_bounds__(256) void gemm_bt(const void* __restrict__ Ap,
                                               const void* __restrict__ Bp,
                                               void* __restrict__ Cp,
                                               int M, int N, int K) {
    __shared__ alignas(16) u16 As[2][128 * BK];
    __shared__ alignas(16) u16 Bs[2][128 * BK];

    const int tid  = threadIdx.x;
    const int lane = tid & 63;
    const int wave = tid >> 6;
    const int wm = (wave >> 1) * 64;
    const int wn = (wave & 1) * 64;
    const int tm = blockIdx.y * 128;
    const int tn = blockIdx.x * 128;
    const int l15 = lane & 15;
    const int l4  = lane >> 4;

    const int srow = tid >> 2;
    const int scol = (tid & 3) * 8;

    floatx4 acc[4][4];
#pragma unroll
    for (int i = 0; i < 4; i++)
#pragma unroll
        for (int j = 0; j < 4; j++) acc[i][j] = fzero();

    if constexpr (!AF32 && !BF32) {
        // Per-lane GLOBAL source is allowed; LDS dest is the wave-uniform base,
        // HW writes lane l at base + l*16 -> LDS element tid*8 overall.
        const u16* Ag = (const u16*)Ap + (size_t)(tm + srow) * K + scol;
        const u16* Bg = (const u16*)Bp + (size_t)(tn + srow) * K + scol;

        auto stage = [&](int buf, int k0) {
            gld_lds16(Ag + k0,                  &As[buf][wave * 512]);
            gld_lds16(Ag + k0 + (size_t)64 * K, &As[buf][2048 + wave * 512]);
            gld_lds16(Bg + k0,                  &Bs[buf][wave * 512]);
            gld_lds16(Bg + k0 + (size_t)64 * K, &Bs[buf][2048 + wave * 512]);
        };

        stage(0, 0);
        __syncthreads();                       // prologue tile landed
        int cur = 0;
        const int nk = K / BK;
        for (int t = 0; t < nk; t++) {
            if (t + 1 < nk) stage(cur ^ 1, (t + 1) * BK);  // issue early

            bf16x8 af[4], bfv[4];
#pragma unroll
            for (int i = 0; i < 4; i++)
                af[i] = *(const bf16x8*)&As[cur][(wm + i * 16 + l15) * BK + l4 * 8];
#pragma unroll
            for (int j = 0; j < 4; j++)
                bfv[j] = *(const bf16x8*)&Bs[cur][(wn + j * 16 + l15) * BK + l4 * 8];
#pragma unroll
            for (int i = 0; i < 4; i++)
#pragma unroll
                for (int j = 0; j < 4; j++)
                    acc[i][j] = __builtin_amdgcn_mfma_f32_16x16x32_bf16(af[i], bfv[j], acc[i][j], 0, 0, 0);

            __syncthreads();                   // reads done + next tile landed
            cur ^= 1;
        }
    } else {
        for (int k0 = 0; k0 < K; k0 += BK) {
            bf16x8 av[2], bv[2];
#pragma unroll
            for (int q = 0; q < 2; q++) {
                av[q] = ld8<AF32>(Ap, (size_t)(tm + srow + q * 64) * K + k0 + scol);
                bv[q] = ld8<BF32>(Bp, (size_t)(tn + srow + q * 64) * K + k0 + scol);
            }
            __syncthreads();
#pragma unroll
            for (int q = 0; q < 2; q++) {
                *(bf16x8*)&As[0][(srow + q * 64) * BK + scol] = av[q];
                *(bf16x8*)&Bs[0][(srow + q * 64) * BK + scol] = bv[q];
            }
            __syncthreads();

            bf16x8 af[4], bfv[4];
#pragma unroll
            for (int i = 0; i < 4; i++)
                af[i] = *(const bf16x8*)&As[0][(wm + i * 16 + l15) * BK + l4 * 8];
#pragma unroll
            for (int j = 0; j < 4; j++)
                bfv[j] = *(const bf16x8*)&Bs[0][(wn + j * 16 + l15) * BK + l4 * 8];
#pragma unroll
            for (int i = 0; i < 4; i++)
#pragma unroll
                for (int j = 0; j < 4; j++)
                    acc[i][j] = __builtin_amdgcn_mfma_f32_16x16x32_bf16(af[i], bfv[j], acc[i][j], 0, 0, 0);
        }
    }

#pragma unroll
    for (int i = 0; i < 4; i++)
#pragma unroll
        for (int j = 0; j < 4; j++)
#pragma unroll
            for (int r = 0; r < 4; r++) {
                int row = tm + wm + i * 16 + l4 * 4 + r;
                int col = tn + wn + j * 16 + l15;
                if constexpr (CF32)
                    ((float*)Cp)[(size_t)row * N + col] = acc[i][j][r];
                else
                    ((u16*)Cp)[(size_t)row * N + col] = f2bf(acc[i][j][r]);
            }
}

// ---------------------------------------------------------------------------
// Flash attention, causal, no online rescaling (scores bounded).
// This round: K/V double-buffered in LDS -> ONE barrier per tile
// (per tile: compute buf[cur] ; commit regs->buf[cur^1] ; issue loads kt+2 ;
// barrier).  V gathered directly from qkv (coalesced 128B rows, L2-resident)
// — transpose_v kernel and vT workspace deleted.
// ---------------------------------------------------------------------------
__global__ __launch_bounds__(256) void attn2(const u16* __restrict__ qkv,
                                             u16* __restrict__ y) {
    const int T = 2048, CW = 3072;
    __shared__ alignas(16) u16 Kb[2][64 * 64];  // K tile [key][dh], dbuf
    __shared__ alignas(16) u16 Vb[2][64 * 64];  // V^T tile [dh][key], dbuf
    __shared__ alignas(16) u16 PB[64 * 64];     // P tile, wave-private rows

    const int tid  = threadIdx.x;
    const int lane = tid & 63;
    const int wave = tid >> 6;
    const int l15 = lane & 15;
    const int l4  = lane >> 4;

    const int bh = blockIdx.x;
    const int qt = 31 - blockIdx.y;            // heavy tiles dispatched first
    const int b = bh >> 4, h = bh & 15;
    const int q0 = qt * 64;

    const size_t base = (size_t)b * T * CW + h * 64;
    const u16* qp = qkv + base;
    const u16* kp = qkv + base + 1024;
    const u16* vp = qkv + base + 2048;

    bf16x8 qf[2];
    {
        int qrow = q0 + wave * 16 + l15;
        qf[0] = *(const bf16x8*)&qp[(size_t)qrow * CW + l4 * 8];
        qf[1] = *(const bf16x8*)&qp[(size_t)qrow * CW + 32 + l4 * 8];
    }

    // all-ones B-fragment for the denominator MFMA
    bf16x8 ones;
#pragma unroll
    for (int i = 0; i < 8; i++) ones[i] = (__bf16)1.0f;

    const float C2 = 0.18033688f;              // (1/8) * log2(e)
    floatx4 Lacc = fzero();                    // rowsum accumulator
    floatx4 Oacc[4];
#pragma unroll
    for (int cf = 0; cf < 4; cf++) Oacc[cf] = fzero();

    const int sr = tid >> 3;                   // 0..31 (K staging row)
    const int sc = tid & 7;                    // 0..7  (K staging 16B chunk)
    const int dh = lane;                       // V gather: lane = dh
    const int tb = wave * 8;                   // V gather: wave's 8-key strip

    bf16x8 kreg[2], vreg[2];
    auto stage_load = [&](int kt) {
        const int t0 = kt * 64;
#pragma unroll
        for (int p = 0; p < 2; p++)
            kreg[p] = *(const bf16x8*)&kp[(size_t)(t0 + sr + p * 32) * CW + sc * 8];
        // V gather: for fixed (p,i), 64 lanes read 64 consecutive dh = 128 B line
#pragma unroll
        for (int p = 0; p < 2; p++) {
            union { u16 u[8]; bf16x8 v; } tmp;
#pragma unroll
            for (int i = 0; i < 8; i++)
                tmp.u[i] = vp[(size_t)(t0 + tb + p * 32 + i) * CW + dh];
            vreg[p] = tmp.v;
        }
    };

    auto commit = [&](int buf) {
#pragma unroll
        for (int p = 0; p < 2; p++)
            *(bf16x8*)swz_ptr(&Kb[buf][0], sr + p * 32, sc * 8) = kreg[p];
#pragma unroll
        for (int p = 0; p < 2; p++)
            *(bf16x8*)swz_ptr(&Vb[buf][0], dh, tb + p * 32) = vreg[p];
    };

    // prologue: tile 0 committed to buf 0, tile 1 in regs
    stage_load(0);
    commit(0);
    if (qt >= 1) stage_load(1);
    __syncthreads();

    for (int kt = 0; kt <= qt; kt++) {
        const int t0 = kt * 64;
        const int cur = kt & 1;
        u16* KP = &Kb[cur][0];
        u16* Vt = &Vb[cur][0];

        // S = Q*K^T, per 16-key block: mask, exp2, P-store (short live ranges)
#pragma unroll
        for (int j = 0; j < 4; j++) {
            bf16x8 k0f = *(const bf16x8*)swz_ptr(KP, j * 16 + l15, l4 * 8);
            bf16x8 k1f = *(const bf16x8*)swz_ptr(KP, j * 16 + l15, 32 + l4 * 8);
            floatx4 s = fzero();
            s = __builtin_amdgcn_mfma_f32_16x16x32_bf16(qf[0], k0f, s, 0, 0, 0);
            s = __builtin_amdgcn_mfma_f32_16x16x32_bf16(qf[1], k1f, s, 0, 0, 0);
            float pj[4];
            if (kt == qt) {
#pragma unroll
                for (int r = 0; r < 4; r++) {
                    int qrow = q0 + wave * 16 + l4 * 4 + r;
                    int krow = t0 + j * 16 + l15;
                    float e = (krow <= qrow) ? s[r] * C2 : -1.0e30f;
                    pj[r] = EXP2F(e);
                }
            } else {
#pragma unroll
                for (int r = 0; r < 4; r++) pj[r] = EXP2F(s[r] * C2);
            }
            // wave-private rows; same-wave DS ordering -> no barrier needed
#pragma unroll
            for (int r = 0; r < 4; r++)
                *swz_ptr(PB, wave * 16 + l4 * 4 + r, j * 16 + l15) = f2bf(pj[r]);
        }

        // P A-frags (this wave's own 16 rows) + PV + denominator MFMA
        bf16x8 pf0 = *(const bf16x8*)swz_ptr(PB, wave * 16 + l15, l4 * 8);
        bf16x8 pf1 = *(const bf16x8*)swz_ptr(PB, wave * 16 + l15, 32 + l4 * 8);
        Lacc = __builtin_amdgcn_mfma_f32_16x16x32_bf16(pf0, ones, Lacc, 0, 0, 0);
        Lacc = __builtin_amdgcn_mfma_f32_16x16x32_bf16(pf1, ones, Lacc, 0, 0, 0);
#pragma unroll
        for (int cf = 0; cf < 4; cf++) {
            bf16x8 v0f = *(const bf16x8*)swz_ptr(Vt, cf * 16 + l15, l4 * 8);
            bf16x8 v1f = *(const bf16x8*)swz_ptr(Vt, cf * 16 + l15, 32 + l4 * 8);
            Oacc[cf] = __builtin_amdgcn_mfma_f32_16x16x32_bf16(pf0, v0f, Oacc[cf], 0, 0, 0);
            Oacc[cf] = __builtin_amdgcn_mfma_f32_16x16x32_bf16(pf1, v1f, Oacc[cf], 0, 0, 0);
        }

        // pipeline: commit tile kt+1 into the other buffer (its regs were
        // loaded one tile ago -> vmcnt satisfied); then fetch tile kt+2.
        if (kt + 1 <= qt) commit(cur ^ 1);
        if (kt + 2 <= qt) stage_load(kt + 2);
        __syncthreads();                       // reads done + commits visible
    }

    // epilogue: Lacc[r] already holds the full row sum in every lane column
#pragma unroll
    for (int r = 0; r < 4; r++) {
        float inv = 1.0f / Lacc[r];
        int qrow = q0 + wave * 16 + l4 * 4 + r;
        size_t orow = ((size_t)b * T + qrow) * 1024 + h * 64;
#pragma unroll
        for (int cf = 0; cf < 4; cf++)
            y[orow + cf * 16 + l15] = f2bf(Oacc[cf][r] * inv);
    }
}

extern "C" void kernel_launch(void* const* d_in, const int* in_sizes, int n_in,
                              void* d_out, int out_size, void* d_ws, size_t ws_size,
                              hipStream_t stream) {
    const float* x      = (const float*)d_in[0];   // [8192,1024] fp32
    const float* w_attn = (const float*)d_in[1];   // [3072,1024] fp32
    const float* w_proj = (const float*)d_in[2];   // [1024,1024] fp32
    float* out = (float*)d_out;                    // [8192,1024] fp32

    const size_t QKV = (size_t)8192 * 3072;
    const size_t Y   = (size_t)8192 * 1024;
    const size_t XB  = (size_t)8192 * 1024;
    const size_t WAB = (size_t)3072 * 1024;
    const size_t WPB = (size_t)1024 * 1024;

    u16* qkv = (u16*)d_ws;
    u16* yb  = qkv + QKV;

    const bool full = ws_size >= (QKV + Y + XB + WAB + WPB) * sizeof(u16); // ~88 MiB
    if (ws_size < (QKV + Y) * sizeof(u16)) return;                         // 64 MiB floor

    dim3 blk(256);
    dim3 g1(3072 / 128, 8192 / 128), g2(1024 / 128, 8192 / 128);
    dim3 ga(64, 32);

    if (full) {
        u16* xb  = yb + Y;                         // xb|wab|wpb contiguous
        cvt_all<<<6144, blk, 0, stream>>>(x, w_attn, w_proj, xb);
        u16* wab = xb + XB;
        u16* wpb = wab + WAB;
        gemm_bt<false, false, false><<<g1, blk, 0, stream>>>(xb, wab, qkv, 8192, 3072, 1024);
        attn2<<<ga, blk, 0, stream>>>(qkv, yb);
        gemm_bt<false, false, true><<<g2, blk, 0, stream>>>(yb, wpb, out, 8192, 1024, 1024);
    } else {
        gemm_bt<true, true, false><<<g1, blk, 0, stream>>>(x, w_attn, qkv, 8192, 3072, 1024);
        attn2<<<ga, blk, 0, stream>>>(qkv, yb);
        gemm_bt<false, true, true><<<g2, blk, 0, stream>>>(yb, w_proj, out, 8192, 1024, 1024);
    }
}